// Round 3
// baseline (1483.333 us; speedup 1.0000x reference)
//
#include <hip/hip_runtime.h>
#include <hip/hip_bf16.h>

typedef short short8 __attribute__((ext_vector_type(8)));
typedef float f32x4 __attribute__((ext_vector_type(4)));

#define DEV __device__ __forceinline__

// ---------------------------------------------------------------- async 16B global->LDS
DEV void async_load16(const void* g, void* l) {
    __builtin_amdgcn_global_load_lds(
        (const __attribute__((address_space(1))) unsigned int*)g,
        (__attribute__((address_space(3))) unsigned int*)l, 16, 0, 0);
}

// ---------------------------------------------------------------- f32 -> bf16 cast
__global__ __launch_bounds__(256) void cast_bf16_kernel(const float* __restrict__ in,
                                                        __hip_bfloat16* __restrict__ out, int n) {
    int i = (blockIdx.x * 256 + threadIdx.x) * 4;
    if (i < n) {
        float4 v = *(const float4*)&in[i];
        out[i + 0] = __float2bfloat16(v.x);
        out[i + 1] = __float2bfloat16(v.y);
        out[i + 2] = __float2bfloat16(v.z);
        out[i + 3] = __float2bfloat16(v.w);
    }
}

// ---------------------------------------------------------------- bf16 MFMA GEMM, C = A(M,K) * B(N,K)^T
template <int EPI>
__global__ __launch_bounds__(256) void gemm_nt(const short* __restrict__ A,
                                               const short* __restrict__ Bm,
                                               float* __restrict__ C,
                                               const float* __restrict__ bias,
                                               int M, int N, int K) {
    __shared__ short lda[128 * 32];
    __shared__ short ldb[128 * 32];
    const int tid  = threadIdx.x;
    const int lane = tid & 63;
    const int wave = tid >> 6;
    const int m0 = blockIdx.x * 128;
    const int n0 = blockIdx.y * 128;
    const int wm = (wave >> 1) * 64;
    const int wn = (wave & 1) * 64;
    f32x4 acc[4][4] = {};

    const int sr = tid >> 2;
    const int sc = (tid & 3) * 8;
    const short* Ab  = A  + (size_t)(m0 + sr) * K + sc;
    const short* Ab2 = Ab + (size_t)64 * K;
    const short* Bb  = Bm + (size_t)(n0 + sr) * K + sc;
    const short* Bb2 = Bb + (size_t)64 * K;
    short* la  = &lda[tid * 8];
    short* la2 = &lda[(tid + 256) * 8];
    short* lb  = &ldb[tid * 8];
    short* lb2 = &ldb[(tid + 256) * 8];

    const int fk = (lane >> 4) * 8;
    const int fr = lane & 15;

    for (int k0 = 0; k0 < K; k0 += 32) {
        async_load16(Ab + k0,  la);
        async_load16(Ab2 + k0, la2);
        async_load16(Bb + k0,  lb);
        async_load16(Bb2 + k0, lb2);
        __syncthreads();
        short8 af[4], bfr[4];
#pragma unroll
        for (int i = 0; i < 4; i++) af[i]  = *(const short8*)&lda[(wm + i * 16 + fr) * 32 + fk];
#pragma unroll
        for (int j = 0; j < 4; j++) bfr[j] = *(const short8*)&ldb[(wn + j * 16 + fr) * 32 + fk];
#pragma unroll
        for (int i = 0; i < 4; i++)
#pragma unroll
            for (int j = 0; j < 4; j++)
                acc[i][j] = __builtin_amdgcn_mfma_f32_16x16x32_bf16(af[i], bfr[j], acc[i][j], 0, 0, 0);
        __syncthreads();
    }

    const int er = (lane >> 4) * 4;
    const int ec = lane & 15;
#pragma unroll
    for (int i = 0; i < 4; i++) {
        const int gr = m0 + wm + i * 16 + er;
#pragma unroll
        for (int j = 0; j < 4; j++) {
            const int gc = n0 + wn + j * 16 + ec;
            float bia = 0.f;
            if constexpr (EPI == 1) bia = bias[gc];
#pragma unroll
            for (int r = 0; r < 4; r++) {
                float v = acc[i][j][r];
                if constexpr (EPI == 1) v = 1.f / (1.f + __expf(-(v + bia)));
                C[(size_t)(gr + r) * N + gc] = v;
            }
        }
    }
}

// ---------------------------------------------------------------- l2norm over rows of 128 (in-place)
__global__ __launch_bounds__(256) void l2norm_kernel(float* __restrict__ buf) {
    const int row  = blockIdx.x * 4 + (threadIdx.x >> 6);
    const int lane = threadIdx.x & 63;
    float* p = &buf[(size_t)row * 128 + lane * 2];
    float2 v = *(float2*)p;
    float s = v.x * v.x + v.y * v.y;
#pragma unroll
    for (int off = 1; off < 64; off <<= 1) s += __shfl_xor(s, off);
    const float inv = 1.f / fmaxf(sqrtf(s), 1e-12f);
    v.x *= inv; v.y *= inv;
    *(float2*)p = v;
}

// ---------------------------------------------------------------- beta = sigmoid(x @ Wb^T + bb), f32 exact
__global__ __launch_bounds__(256) void beta_kernel(const float* __restrict__ x,
                                                   const float* __restrict__ Wb,
                                                   const float* __restrict__ bb,
                                                   float* __restrict__ beta) {
    __shared__ float xs[16 * 132];
    const int tid = threadIdx.x;
    const float* xr = &x[(size_t)blockIdx.x * 2048];
#pragma unroll
    for (int i = tid; i < 512; i += 256) {
        float4 v = ((const float4*)xr)[i];
        const int j = i * 4;
        *(float4*)&xs[(j >> 7) * 132 + (j & 127)] = v;
    }
    __syncthreads();
    const int n = tid >> 4, ks = tid & 15;
    const float* w  = &Wb[(size_t)n * 2048 + ks * 128];
    const float* xx = &xs[ks * 132];
    float s = 0.f;
#pragma unroll 8
    for (int j = 0; j < 128; j++) s += xx[j] * w[j];
    s += __shfl_xor(s, 1); s += __shfl_xor(s, 2);
    s += __shfl_xor(s, 4); s += __shfl_xor(s, 8);
    if (ks == 0) beta[(size_t)blockIdx.x * 16 + n] = 1.f / (1.f + __expf(-(s + bb[n])));
}

// ---------------------------------------------------------------- sequential recurrence, wave-private
// 512 blocks x 256 thr = 2048 waves (2/SIMD). Wave = 2 rows x 32 lanes, 4 state f32/lane.
// XCD-local: bh = blockIdx&31 -> all 16 blocks of a bh land on XCD bh%8.
// 3-set register rotation: loads for t+2 issued at top of body t (no LDS, no barriers).
__global__ __launch_bounds__(256) void recurrence_kernel(
        const float* __restrict__ S0, const float* __restrict__ qn, const float* __restrict__ kn,
        const float* __restrict__ vv, const float* __restrict__ adec, const float* __restrict__ bet,
        const float* __restrict__ gg, __hip_bfloat16* __restrict__ o) {
    const int bh = blockIdx.x & 31;        // XCD = bh % 8
    const int jb = blockIdx.x >> 5;        // 0..15
    const int b = bh >> 4, h = bh & 15;
    const int lane = threadIdx.x & 63;
    const int wave = threadIdx.x >> 6;
    const int r = lane >> 5;               // row within wave (0..1)
    const int c = lane & 31;               // col chunk (4 f32)
    const int i = jb * 8 + wave * 2 + r;   // 0..127

    float S[4];
    *(float4*)S = *(const float4*)&S0[((size_t)(bh * 128 + i)) * 128 + c * 4];

    const size_t hb = (size_t)(b * 2048) * 16 + h;
    const size_t STEP = 16 * 128;
    const float* kp = kn + hb * 128 + c * 4;
    const float* qp = qn + hb * 128 + c * 4;
    const float* vp = vv   + hb * 128 + i;
    const float* ap = adec + hb * 128 + i;
    const float* gp = gg   + hb * 128 + i;
    const float* bp = bet + hb;
    __hip_bfloat16* op = o + hb * 128 + i;

    float kA[4], qA[4], vA, aA, gA, bA;
    float kB[4], qB[4], vB, aB, gB, bB;
    float kC[4], qC[4], vC, aC, gC, bC;
    *(float4*)kA = *(const float4*)kp;
    *(float4*)qA = *(const float4*)qp;
    vA = vp[0]; aA = ap[0]; gA = gp[0]; bA = bp[0];
    *(float4*)kB = *(const float4*)(kp + STEP);
    *(float4*)qB = *(const float4*)(qp + STEP);
    vB = vp[STEP]; aB = ap[STEP]; gB = gp[STEP]; bB = bp[16];

#define RBODY(T, KC, QC, VC, AC, GC, BC, KP, QP, VP, AP, GP, BP)               \
    {                                                                          \
        const int tp_ = ((T) + 2 < 2048) ? (T) + 2 : 2047;                     \
        const size_t nb_ = (size_t)tp_ * STEP;                                 \
        *(float4*)KP = *(const float4*)(kp + nb_);                             \
        *(float4*)QP = *(const float4*)(qp + nb_);                             \
        VP = vp[nb_]; AP = ap[nb_]; GP = gp[nb_]; BP = bp[(size_t)tp_ * 16];   \
        float p0 = S[0] * KC[0], p1 = S[1] * KC[1];                            \
        p0 = fmaf(S[2], KC[2], p0); p1 = fmaf(S[3], KC[3], p1);                \
        float p = p0 + p1;                                                     \
        p += __shfl_xor(p, 1); p += __shfl_xor(p, 2);                          \
        p += __shfl_xor(p, 4); p += __shfl_xor(p, 8);                          \
        p += __shfl_xor(p, 16);                                                \
        const float coef = BC * (VC - p);                                      \
        S[0] = fmaf(AC, S[0], coef * KC[0]);                                   \
        S[1] = fmaf(AC, S[1], coef * KC[1]);                                   \
        S[2] = fmaf(AC, S[2], coef * KC[2]);                                   \
        S[3] = fmaf(AC, S[3], coef * KC[3]);                                   \
        float o0 = S[0] * QC[0], o1 = S[1] * QC[1];                            \
        o0 = fmaf(S[2], QC[2], o0); o1 = fmaf(S[3], QC[3], o1);                \
        float ov = o0 + o1;                                                    \
        ov += __shfl_xor(ov, 1); ov += __shfl_xor(ov, 2);                      \
        ov += __shfl_xor(ov, 4); ov += __shfl_xor(ov, 8);                      \
        ov += __shfl_xor(ov, 16);                                              \
        if (c == 0 && (T) < 2048)                                              \
            op[(size_t)(T) * STEP] = __float2bfloat16(ov * GC);                \
    }

    for (int t = 0; t < 2047; t += 3) {
        RBODY(t,     kA, qA, vA, aA, gA, bA, kC, qC, vC, aC, gC, bC);
        RBODY(t + 1, kB, qB, vB, aB, gB, bB, kA, qA, vA, aA, gA, bA);
        RBODY(t + 2, kC, qC, vC, aC, gC, bC, kB, qB, vB, aB, gB, bB);
    }
#undef RBODY
}

// ----------------------------------------------------------------
extern "C" void kernel_launch(void* const* d_in, const int* in_sizes, int n_in,
                              void* d_out, int out_size, void* d_ws, size_t ws_size,
                              hipStream_t stream) {
    const float* x  = (const float*)d_in[0];
    const float* S0 = (const float*)d_in[1];
    const float* Wq = (const float*)d_in[2];
    const float* Wk = (const float*)d_in[3];
    const float* Wv = (const float*)d_in[4];
    const float* Wa = (const float*)d_in[5];
    const float* ba = (const float*)d_in[6];
    const float* Wb = (const float*)d_in[7];
    const float* bb = (const float*)d_in[8];
    const float* Wg = (const float*)d_in[9];
    const float* bg = (const float*)d_in[10];
    const float* Wo = (const float*)d_in[11];
    float* out = (float*)d_out;

    const int M = 4096, N = 2048, K = 2048;

    size_t off = 0;
    auto alloc = [&](size_t bytes) {
        void* p = (char*)d_ws + off;
        off += (bytes + 255) & ~(size_t)255;
        return p;
    };
    short* x_bf  = (short*)alloc((size_t)M * K * 2);  // later reused as o_bf
    short* Wq_bf = (short*)alloc((size_t)N * K * 2);
    short* Wk_bf = (short*)alloc((size_t)N * K * 2);
    short* Wv_bf = (short*)alloc((size_t)N * K * 2);
    short* Wa_bf = (short*)alloc((size_t)N * K * 2);
    short* Wg_bf = (short*)alloc((size_t)N * K * 2);
    short* Wo_bf = (short*)alloc((size_t)N * K * 2);
    float* qb    = (float*)alloc((size_t)M * N * 4);
    float* kb    = (float*)alloc((size_t)M * N * 4);
    float* vb    = (float*)alloc((size_t)M * N * 4);
    float* ab    = (float*)alloc((size_t)M * N * 4);
    float* gb    = (float*)alloc((size_t)M * N * 4);
    float* betab = (float*)alloc((size_t)M * 16 * 4);

    cast_bf16_kernel<<<dim3((M * K / 4 + 255) / 256), dim3(256), 0, stream>>>(x,  (__hip_bfloat16*)x_bf,  M * K);
    cast_bf16_kernel<<<dim3((N * K / 4 + 255) / 256), dim3(256), 0, stream>>>(Wq, (__hip_bfloat16*)Wq_bf, N * K);
    cast_bf16_kernel<<<dim3((N * K / 4 + 255) / 256), dim3(256), 0, stream>>>(Wk, (__hip_bfloat16*)Wk_bf, N * K);
    cast_bf16_kernel<<<dim3((N * K / 4 + 255) / 256), dim3(256), 0, stream>>>(Wv, (__hip_bfloat16*)Wv_bf, N * K);
    cast_bf16_kernel<<<dim3((N * K / 4 + 255) / 256), dim3(256), 0, stream>>>(Wa, (__hip_bfloat16*)Wa_bf, N * K);
    cast_bf16_kernel<<<dim3((N * K / 4 + 255) / 256), dim3(256), 0, stream>>>(Wg, (__hip_bfloat16*)Wg_bf, N * K);
    cast_bf16_kernel<<<dim3((N * K / 4 + 255) / 256), dim3(256), 0, stream>>>(Wo, (__hip_bfloat16*)Wo_bf, N * K);

    dim3 gdim(M / 128, N / 128), bdim(256);
    gemm_nt<0><<<gdim, bdim, 0, stream>>>(x_bf, Wq_bf, qb, nullptr, M, N, K);
    gemm_nt<0><<<gdim, bdim, 0, stream>>>(x_bf, Wk_bf, kb, nullptr, M, N, K);
    gemm_nt<0><<<gdim, bdim, 0, stream>>>(x_bf, Wv_bf, vb, nullptr, M, N, K);
    gemm_nt<1><<<gdim, bdim, 0, stream>>>(x_bf, Wa_bf, ab, ba, M, N, K);
    gemm_nt<1><<<gdim, bdim, 0, stream>>>(x_bf, Wg_bf, gb, bg, M, N, K);

    l2norm_kernel<<<dim3(M * 16 / 4), dim3(256), 0, stream>>>(qb);
    l2norm_kernel<<<dim3(M * 16 / 4), dim3(256), 0, stream>>>(kb);
    beta_kernel<<<dim3(M), dim3(256), 0, stream>>>(x, Wb, bb, betab);

    __hip_bfloat16* o_bf = (__hip_bfloat16*)x_bf;
    recurrence_kernel<<<dim3(512), dim3(256), 0, stream>>>(S0, qb, kb, vb, ab, betab, gb, o_bf);

    gemm_nt<0><<<gdim, bdim, 0, stream>>>((const short*)o_bf, Wo_bf, out, nullptr, M, N, K);
}

// Round 4
// 1044.269 us; speedup vs baseline: 1.4205x; 1.4205x over previous
//
#include <hip/hip_runtime.h>
#include <hip/hip_bf16.h>

typedef short short8 __attribute__((ext_vector_type(8)));
typedef float f32x4 __attribute__((ext_vector_type(4)));

#define DEV __device__ __forceinline__

// ---------------------------------------------------------------- async 16B global->LDS
DEV void async_load16(const void* g, void* l) {
    __builtin_amdgcn_global_load_lds(
        (const __attribute__((address_space(1))) unsigned int*)g,
        (__attribute__((address_space(3))) unsigned int*)l, 16, 0, 0);
}

// ---------------------------------------------------------------- DPP 16-lane sum butterfly
// v_add_f32 + row_ror:N (VALU pipe, ~4-8 cyc) instead of ds_bpermute (~120 cyc).
// Rotational butterfly ror 8,4,2,1 -> every lane of each 16-lane row holds the row sum.
template <int CTRL>
DEV float dpp_add16(float v) {
    int t = __builtin_amdgcn_update_dpp(0, __float_as_int(v), CTRL, 0xf, 0xf, true);
    return v + __int_as_float(t);
}
DEV float row_sum16(float v) {
    v = dpp_add16<0x128>(v);  // row_ror:8
    v = dpp_add16<0x124>(v);  // row_ror:4
    v = dpp_add16<0x122>(v);  // row_ror:2
    v = dpp_add16<0x121>(v);  // row_ror:1
    return v;
}

// ---------------------------------------------------------------- f32 -> bf16 cast
__global__ __launch_bounds__(256) void cast_bf16_kernel(const float* __restrict__ in,
                                                        __hip_bfloat16* __restrict__ out, int n) {
    int i = (blockIdx.x * 256 + threadIdx.x) * 4;
    if (i < n) {
        float4 v = *(const float4*)&in[i];
        out[i + 0] = __float2bfloat16(v.x);
        out[i + 1] = __float2bfloat16(v.y);
        out[i + 2] = __float2bfloat16(v.z);
        out[i + 3] = __float2bfloat16(v.w);
    }
}

// ---------------------------------------------------------------- bf16 MFMA GEMM, C = A(M,K) * B(N,K)^T
template <int EPI>
__global__ __launch_bounds__(256) void gemm_nt(const short* __restrict__ A,
                                               const short* __restrict__ Bm,
                                               float* __restrict__ C,
                                               const float* __restrict__ bias,
                                               int M, int N, int K) {
    __shared__ short lda[128 * 32];
    __shared__ short ldb[128 * 32];
    const int tid  = threadIdx.x;
    const int lane = tid & 63;
    const int wave = tid >> 6;
    const int m0 = blockIdx.x * 128;
    const int n0 = blockIdx.y * 128;
    const int wm = (wave >> 1) * 64;
    const int wn = (wave & 1) * 64;
    f32x4 acc[4][4] = {};

    const int sr = tid >> 2;
    const int sc = (tid & 3) * 8;
    const short* Ab  = A  + (size_t)(m0 + sr) * K + sc;
    const short* Ab2 = Ab + (size_t)64 * K;
    const short* Bb  = Bm + (size_t)(n0 + sr) * K + sc;
    const short* Bb2 = Bb + (size_t)64 * K;
    short* la  = &lda[tid * 8];
    short* la2 = &lda[(tid + 256) * 8];
    short* lb  = &ldb[tid * 8];
    short* lb2 = &ldb[(tid + 256) * 8];

    const int fk = (lane >> 4) * 8;
    const int fr = lane & 15;

    for (int k0 = 0; k0 < K; k0 += 32) {
        async_load16(Ab + k0,  la);
        async_load16(Ab2 + k0, la2);
        async_load16(Bb + k0,  lb);
        async_load16(Bb2 + k0, lb2);
        __syncthreads();
        short8 af[4], bfr[4];
#pragma unroll
        for (int i = 0; i < 4; i++) af[i]  = *(const short8*)&lda[(wm + i * 16 + fr) * 32 + fk];
#pragma unroll
        for (int j = 0; j < 4; j++) bfr[j] = *(const short8*)&ldb[(wn + j * 16 + fr) * 32 + fk];
#pragma unroll
        for (int i = 0; i < 4; i++)
#pragma unroll
            for (int j = 0; j < 4; j++)
                acc[i][j] = __builtin_amdgcn_mfma_f32_16x16x32_bf16(af[i], bfr[j], acc[i][j], 0, 0, 0);
        __syncthreads();
    }

    const int er = (lane >> 4) * 4;
    const int ec = lane & 15;
#pragma unroll
    for (int i = 0; i < 4; i++) {
        const int gr = m0 + wm + i * 16 + er;
#pragma unroll
        for (int j = 0; j < 4; j++) {
            const int gc = n0 + wn + j * 16 + ec;
            float bia = 0.f;
            if constexpr (EPI == 1) bia = bias[gc];
#pragma unroll
            for (int r = 0; r < 4; r++) {
                float v = acc[i][j][r];
                if constexpr (EPI == 1) v = 1.f / (1.f + __expf(-(v + bia)));
                C[(size_t)(gr + r) * N + gc] = v;
            }
        }
    }
}

// ---------------------------------------------------------------- l2norm over rows of 128 (in-place)
__global__ __launch_bounds__(256) void l2norm_kernel(float* __restrict__ buf) {
    const int row  = blockIdx.x * 4 + (threadIdx.x >> 6);
    const int lane = threadIdx.x & 63;
    float* p = &buf[(size_t)row * 128 + lane * 2];
    float2 v = *(float2*)p;
    float s = v.x * v.x + v.y * v.y;
#pragma unroll
    for (int off = 1; off < 64; off <<= 1) s += __shfl_xor(s, off);
    const float inv = 1.f / fmaxf(sqrtf(s), 1e-12f);
    v.x *= inv; v.y *= inv;
    *(float2*)p = v;
}

// ---------------------------------------------------------------- beta = sigmoid(x @ Wb^T + bb), f32 exact
__global__ __launch_bounds__(256) void beta_kernel(const float* __restrict__ x,
                                                   const float* __restrict__ Wb,
                                                   const float* __restrict__ bb,
                                                   float* __restrict__ beta) {
    __shared__ float xs[16 * 132];
    const int tid = threadIdx.x;
    const float* xr = &x[(size_t)blockIdx.x * 2048];
#pragma unroll
    for (int i = tid; i < 512; i += 256) {
        float4 v = ((const float4*)xr)[i];
        const int j = i * 4;
        *(float4*)&xs[(j >> 7) * 132 + (j & 127)] = v;
    }
    __syncthreads();
    const int n = tid >> 4, ks = tid & 15;
    const float* w  = &Wb[(size_t)n * 2048 + ks * 128];
    const float* xx = &xs[ks * 132];
    float s = 0.f;
#pragma unroll 8
    for (int j = 0; j < 128; j++) s += xx[j] * w[j];
    s += __shfl_xor(s, 1); s += __shfl_xor(s, 2);
    s += __shfl_xor(s, 4); s += __shfl_xor(s, 8);
    if (ks == 0) beta[(size_t)blockIdx.x * 16 + n] = 1.f / (1.f + __expf(-(s + bb[n])));
}

// ---------------------------------------------------------------- sequential recurrence, wave-private
// 256 blocks x 4 waves = 1024 waves. Wave = 4 rows x 16 lanes, 8 state f32/lane.
// bh = blockIdx&31 -> all 8 blocks of a bh land on XCD bh%8 (L2-local k/q/v/a/g).
// Reductions: DPP row_ror butterflies (VALU pipe), no LDS, no barriers.
// 3-step-ahead register prefetch (4 buffers) covers L2/L3 hit latency.
__global__ __launch_bounds__(256) void recurrence_kernel(
        const float* __restrict__ S0, const float* __restrict__ qn, const float* __restrict__ kn,
        const float* __restrict__ vv, const float* __restrict__ adec, const float* __restrict__ bet,
        const float* __restrict__ gg, __hip_bfloat16* __restrict__ o) {
    const int bh  = blockIdx.x & 31;   // XCD = bh % 8
    const int rb8 = blockIdx.x >> 5;   // 0..7
    const int b = bh >> 4, h = bh & 15;
    const int lane = threadIdx.x & 63;
    const int wave = threadIdx.x >> 6;
    const int r = lane >> 4;               // row within wave (0..3)
    const int c = lane & 15;               // col chunk (8 f32)
    const int i = rb8 * 16 + wave * 4 + r; // 0..127

    float S[8];
    {
        const float* s0 = &S0[((size_t)(bh * 128 + i)) * 128 + c * 8];
        *(float4*)&S[0] = *(const float4*)s0;
        *(float4*)&S[4] = *(const float4*)(s0 + 4);
    }

    const size_t hb = (size_t)(b * 2048) * 16 + h;
    const size_t STEP = 16 * 128;
    const float* kp = kn + hb * 128 + c * 8;
    const float* qp = qn + hb * 128 + c * 8;
    const float* vp = vv   + hb * 128 + i;
    const float* ap = adec + hb * 128 + i;
    const float* gp = gg   + hb * 128 + i;
    const float* bp = bet + hb;
    __hip_bfloat16* op = o + hb * 128 + i;

    float kA[8], qA[8], vA, aA, gA, bA;
    float kB[8], qB[8], vB, aB, gB, bB;
    float kC[8], qC[8], vC, aC, gC, bC;
    float kD[8], qD[8], vD, aD, gD, bD;
    *(float4*)&kA[0] = *(const float4*)(kp);            *(float4*)&kA[4] = *(const float4*)(kp + 4);
    *(float4*)&qA[0] = *(const float4*)(qp);            *(float4*)&qA[4] = *(const float4*)(qp + 4);
    vA = vp[0]; aA = ap[0]; gA = gp[0]; bA = bp[0];
    *(float4*)&kB[0] = *(const float4*)(kp + STEP);     *(float4*)&kB[4] = *(const float4*)(kp + STEP + 4);
    *(float4*)&qB[0] = *(const float4*)(qp + STEP);     *(float4*)&qB[4] = *(const float4*)(qp + STEP + 4);
    vB = vp[STEP]; aB = ap[STEP]; gB = gp[STEP]; bB = bp[16];
    *(float4*)&kC[0] = *(const float4*)(kp + 2 * STEP); *(float4*)&kC[4] = *(const float4*)(kp + 2 * STEP + 4);
    *(float4*)&qC[0] = *(const float4*)(qp + 2 * STEP); *(float4*)&qC[4] = *(const float4*)(qp + 2 * STEP + 4);
    vC = vp[2 * STEP]; aC = ap[2 * STEP]; gC = gp[2 * STEP]; bC = bp[32];

#define RBODY(T, KC, QC, VC, AC, GC, BC, KP, QP, VP, AP, GP, BP)                          \
    {                                                                                     \
        const int tp_ = ((T) + 3 < 2048) ? (T) + 3 : 2047;                                \
        const size_t nb_ = (size_t)tp_ * STEP;                                            \
        *(float4*)&KP[0] = *(const float4*)(kp + nb_);                                    \
        *(float4*)&KP[4] = *(const float4*)(kp + nb_ + 4);                                \
        *(float4*)&QP[0] = *(const float4*)(qp + nb_);                                    \
        *(float4*)&QP[4] = *(const float4*)(qp + nb_ + 4);                                \
        VP = vp[nb_]; AP = ap[nb_]; GP = gp[nb_]; BP = bp[(size_t)tp_ * 16];              \
        float p0 = S[0] * KC[0], p1 = S[1] * KC[1], p2 = S[2] * KC[2], p3 = S[3] * KC[3]; \
        p0 = fmaf(S[4], KC[4], p0); p1 = fmaf(S[5], KC[5], p1);                           \
        p2 = fmaf(S[6], KC[6], p2); p3 = fmaf(S[7], KC[7], p3);                           \
        float p = row_sum16((p0 + p1) + (p2 + p3));                                       \
        const float coef = BC * (VC - p);                                                 \
        _Pragma("unroll") for (int j = 0; j < 8; j++)                                     \
            S[j] = fmaf(AC, S[j], coef * KC[j]);                                          \
        float o0 = S[0] * QC[0], o1 = S[1] * QC[1], o2 = S[2] * QC[2], o3 = S[3] * QC[3]; \
        o0 = fmaf(S[4], QC[4], o0); o1 = fmaf(S[5], QC[5], o1);                           \
        o2 = fmaf(S[6], QC[6], o2); o3 = fmaf(S[7], QC[7], o3);                           \
        float ov = row_sum16((o0 + o1) + (o2 + o3));                                      \
        if (c == 0) op[(size_t)(T) * STEP] = __float2bfloat16(ov * GC);                   \
    }

    for (int t = 0; t < 2048; t += 4) {
        RBODY(t,     kA, qA, vA, aA, gA, bA, kD, qD, vD, aD, gD, bD);
        RBODY(t + 1, kB, qB, vB, aB, gB, bB, kA, qA, vA, aA, gA, bA);
        RBODY(t + 2, kC, qC, vC, aC, gC, bC, kB, qB, vB, aB, gB, bB);
        RBODY(t + 3, kD, qD, vD, aD, gD, bD, kC, qC, vC, aC, gC, bC);
    }
#undef RBODY
}

// ----------------------------------------------------------------
extern "C" void kernel_launch(void* const* d_in, const int* in_sizes, int n_in,
                              void* d_out, int out_size, void* d_ws, size_t ws_size,
                              hipStream_t stream) {
    const float* x  = (const float*)d_in[0];
    const float* S0 = (const float*)d_in[1];
    const float* Wq = (const float*)d_in[2];
    const float* Wk = (const float*)d_in[3];
    const float* Wv = (const float*)d_in[4];
    const float* Wa = (const float*)d_in[5];
    const float* ba = (const float*)d_in[6];
    const float* Wb = (const float*)d_in[7];
    const float* bb = (const float*)d_in[8];
    const float* Wg = (const float*)d_in[9];
    const float* bg = (const float*)d_in[10];
    const float* Wo = (const float*)d_in[11];
    float* out = (float*)d_out;

    const int M = 4096, N = 2048, K = 2048;

    size_t off = 0;
    auto alloc = [&](size_t bytes) {
        void* p = (char*)d_ws + off;
        off += (bytes + 255) & ~(size_t)255;
        return p;
    };
    short* x_bf  = (short*)alloc((size_t)M * K * 2);  // later reused as o_bf
    short* Wq_bf = (short*)alloc((size_t)N * K * 2);
    short* Wk_bf = (short*)alloc((size_t)N * K * 2);
    short* Wv_bf = (short*)alloc((size_t)N * K * 2);
    short* Wa_bf = (short*)alloc((size_t)N * K * 2);
    short* Wg_bf = (short*)alloc((size_t)N * K * 2);
    short* Wo_bf = (short*)alloc((size_t)N * K * 2);
    float* qb    = (float*)alloc((size_t)M * N * 4);
    float* kb    = (float*)alloc((size_t)M * N * 4);
    float* vb    = (float*)alloc((size_t)M * N * 4);
    float* ab    = (float*)alloc((size_t)M * N * 4);
    float* gb    = (float*)alloc((size_t)M * N * 4);
    float* betab = (float*)alloc((size_t)M * 16 * 4);

    cast_bf16_kernel<<<dim3((M * K / 4 + 255) / 256), dim3(256), 0, stream>>>(x,  (__hip_bfloat16*)x_bf,  M * K);
    cast_bf16_kernel<<<dim3((N * K / 4 + 255) / 256), dim3(256), 0, stream>>>(Wq, (__hip_bfloat16*)Wq_bf, N * K);
    cast_bf16_kernel<<<dim3((N * K / 4 + 255) / 256), dim3(256), 0, stream>>>(Wk, (__hip_bfloat16*)Wk_bf, N * K);
    cast_bf16_kernel<<<dim3((N * K / 4 + 255) / 256), dim3(256), 0, stream>>>(Wv, (__hip_bfloat16*)Wv_bf, N * K);
    cast_bf16_kernel<<<dim3((N * K / 4 + 255) / 256), dim3(256), 0, stream>>>(Wa, (__hip_bfloat16*)Wa_bf, N * K);
    cast_bf16_kernel<<<dim3((N * K / 4 + 255) / 256), dim3(256), 0, stream>>>(Wg, (__hip_bfloat16*)Wg_bf, N * K);
    cast_bf16_kernel<<<dim3((N * K / 4 + 255) / 256), dim3(256), 0, stream>>>(Wo, (__hip_bfloat16*)Wo_bf, N * K);

    dim3 gdim(M / 128, N / 128), bdim(256);
    gemm_nt<0><<<gdim, bdim, 0, stream>>>(x_bf, Wq_bf, qb, nullptr, M, N, K);
    gemm_nt<0><<<gdim, bdim, 0, stream>>>(x_bf, Wk_bf, kb, nullptr, M, N, K);
    gemm_nt<0><<<gdim, bdim, 0, stream>>>(x_bf, Wv_bf, vb, nullptr, M, N, K);
    gemm_nt<1><<<gdim, bdim, 0, stream>>>(x_bf, Wa_bf, ab, ba, M, N, K);
    gemm_nt<1><<<gdim, bdim, 0, stream>>>(x_bf, Wg_bf, gb, bg, M, N, K);

    l2norm_kernel<<<dim3(M * 16 / 4), dim3(256), 0, stream>>>(qb);
    l2norm_kernel<<<dim3(M * 16 / 4), dim3(256), 0, stream>>>(kb);
    beta_kernel<<<dim3(M), dim3(256), 0, stream>>>(x, Wb, bb, betab);

    __hip_bfloat16* o_bf = (__hip_bfloat16*)x_bf;
    recurrence_kernel<<<dim3(256), dim3(256), 0, stream>>>(S0, qb, kb, vb, ab, betab, gb, o_bf);

    gemm_nt<0><<<gdim, bdim, 0, stream>>>((const short*)o_bf, Wo_bf, out, nullptr, M, N, K);
}

// Round 5
// 963.339 us; speedup vs baseline: 1.5398x; 1.0840x over previous
//
#include <hip/hip_runtime.h>
#include <hip/hip_bf16.h>

typedef short short8 __attribute__((ext_vector_type(8)));
typedef float f32x4 __attribute__((ext_vector_type(4)));

#define DEV __device__ __forceinline__

// ---------------------------------------------------------------- async 16B global->LDS
DEV void async_load16(const void* g, void* l) {
    __builtin_amdgcn_global_load_lds(
        (const __attribute__((address_space(1))) unsigned int*)g,
        (__attribute__((address_space(3))) unsigned int*)l, 16, 0, 0);
}

// ---------------------------------------------------------------- DPP 16-lane sum butterfly
template <int CTRL>
DEV float dpp_add16(float v) {
    int t = __builtin_amdgcn_update_dpp(0, __float_as_int(v), CTRL, 0xf, 0xf, true);
    return v + __int_as_float(t);
}
DEV float row_sum16(float v) {
    v = dpp_add16<0x128>(v);  // row_ror:8
    v = dpp_add16<0x124>(v);  // row_ror:4
    v = dpp_add16<0x122>(v);  // row_ror:2
    v = dpp_add16<0x121>(v);  // row_ror:1
    return v;
}

// ---------------------------------------------------------------- f32 -> bf16 cast
__global__ __launch_bounds__(256) void cast_bf16_kernel(const float* __restrict__ in,
                                                        __hip_bfloat16* __restrict__ out, int n) {
    int i = (blockIdx.x * 256 + threadIdx.x) * 4;
    if (i < n) {
        float4 v = *(const float4*)&in[i];
        out[i + 0] = __float2bfloat16(v.x);
        out[i + 1] = __float2bfloat16(v.y);
        out[i + 2] = __float2bfloat16(v.z);
        out[i + 3] = __float2bfloat16(v.w);
    }
}

// ---------------------------------------------------------------- bf16 MFMA GEMM, C = A(M,K) * B(N,K)^T
template <int EPI>
__global__ __launch_bounds__(256) void gemm_nt(const short* __restrict__ A,
                                               const short* __restrict__ Bm,
                                               float* __restrict__ C,
                                               const float* __restrict__ bias,
                                               int M, int N, int K) {
    __shared__ short lda[128 * 32];
    __shared__ short ldb[128 * 32];
    const int tid  = threadIdx.x;
    const int lane = tid & 63;
    const int wave = tid >> 6;
    const int m0 = blockIdx.x * 128;
    const int n0 = blockIdx.y * 128;
    const int wm = (wave >> 1) * 64;
    const int wn = (wave & 1) * 64;
    f32x4 acc[4][4] = {};

    const int sr = tid >> 2;
    const int sc = (tid & 3) * 8;
    const short* Ab  = A  + (size_t)(m0 + sr) * K + sc;
    const short* Ab2 = Ab + (size_t)64 * K;
    const short* Bb  = Bm + (size_t)(n0 + sr) * K + sc;
    const short* Bb2 = Bb + (size_t)64 * K;
    short* la  = &lda[tid * 8];
    short* la2 = &lda[(tid + 256) * 8];
    short* lb  = &ldb[tid * 8];
    short* lb2 = &ldb[(tid + 256) * 8];

    const int fk = (lane >> 4) * 8;
    const int fr = lane & 15;

    for (int k0 = 0; k0 < K; k0 += 32) {
        async_load16(Ab + k0,  la);
        async_load16(Ab2 + k0, la2);
        async_load16(Bb + k0,  lb);
        async_load16(Bb2 + k0, lb2);
        __syncthreads();
        short8 af[4], bfr[4];
#pragma unroll
        for (int i = 0; i < 4; i++) af[i]  = *(const short8*)&lda[(wm + i * 16 + fr) * 32 + fk];
#pragma unroll
        for (int j = 0; j < 4; j++) bfr[j] = *(const short8*)&ldb[(wn + j * 16 + fr) * 32 + fk];
#pragma unroll
        for (int i = 0; i < 4; i++)
#pragma unroll
            for (int j = 0; j < 4; j++)
                acc[i][j] = __builtin_amdgcn_mfma_f32_16x16x32_bf16(af[i], bfr[j], acc[i][j], 0, 0, 0);
        __syncthreads();
    }

    const int er = (lane >> 4) * 4;
    const int ec = lane & 15;
#pragma unroll
    for (int i = 0; i < 4; i++) {
        const int gr = m0 + wm + i * 16 + er;
#pragma unroll
        for (int j = 0; j < 4; j++) {
            const int gc = n0 + wn + j * 16 + ec;
            float bia = 0.f;
            if constexpr (EPI == 1) bia = bias[gc];
#pragma unroll
            for (int r = 0; r < 4; r++) {
                float v = acc[i][j][r];
                if constexpr (EPI == 1) v = 1.f / (1.f + __expf(-(v + bia)));
                C[(size_t)(gr + r) * N + gc] = v;
            }
        }
    }
}

// ---------------------------------------------------------------- l2norm over rows of 128 (in-place)
__global__ __launch_bounds__(256) void l2norm_kernel(float* __restrict__ buf) {
    const int row  = blockIdx.x * 4 + (threadIdx.x >> 6);
    const int lane = threadIdx.x & 63;
    float* p = &buf[(size_t)row * 128 + lane * 2];
    float2 v = *(float2*)p;
    float s = v.x * v.x + v.y * v.y;
#pragma unroll
    for (int off = 1; off < 64; off <<= 1) s += __shfl_xor(s, off);
    const float inv = 1.f / fmaxf(sqrtf(s), 1e-12f);
    v.x *= inv; v.y *= inv;
    *(float2*)p = v;
}

// ---------------------------------------------------------------- beta = sigmoid(x @ Wb^T + bb), f32 exact
__global__ __launch_bounds__(256) void beta_kernel(const float* __restrict__ x,
                                                   const float* __restrict__ Wb,
                                                   const float* __restrict__ bb,
                                                   float* __restrict__ beta) {
    __shared__ float xs[16 * 132];
    const int tid = threadIdx.x;
    const float* xr = &x[(size_t)blockIdx.x * 2048];
#pragma unroll
    for (int i = tid; i < 512; i += 256) {
        float4 v = ((const float4*)xr)[i];
        const int j = i * 4;
        *(float4*)&xs[(j >> 7) * 132 + (j & 127)] = v;
    }
    __syncthreads();
    const int n = tid >> 4, ks = tid & 15;
    const float* w  = &Wb[(size_t)n * 2048 + ks * 128];
    const float* xx = &xs[ks * 132];
    float s = 0.f;
#pragma unroll 8
    for (int j = 0; j < 128; j++) s += xx[j] * w[j];
    s += __shfl_xor(s, 1); s += __shfl_xor(s, 2);
    s += __shfl_xor(s, 4); s += __shfl_xor(s, 8);
    if (ks == 0) beta[(size_t)blockIdx.x * 16 + n] = 1.f / (1.f + __expf(-(s + bb[n])));
}

// ---------------------------------------------------------------- sequential recurrence, wave-private
// 256 blocks x 4 waves = 1024 waves (1/SIMD, grid-limited). Wave = 4 rows x 16 lanes,
// 8 state f32/lane. bh = blockIdx&31 -> XCD-local k/q/v/a/g (L2-resident).
// __launch_bounds__(256,1): lift VGPR cap so the 4-set register pipeline survives
// (R3's VGPR=60 proved the default 8-wave heuristic sank the prefetch loads).
// Packed f32x4 math -> v_pk_fma_f32. DPP row_ror butterflies for the 16-lane reduces.
__global__ __launch_bounds__(256, 1) void recurrence_kernel(
        const float* __restrict__ S0, const float* __restrict__ qn, const float* __restrict__ kn,
        const float* __restrict__ vv, const float* __restrict__ adec, const float* __restrict__ bet,
        const float* __restrict__ gg, __hip_bfloat16* __restrict__ o) {
    const int bh  = blockIdx.x & 31;   // XCD = bh % 8
    const int rb8 = blockIdx.x >> 5;   // 0..7
    const int b = bh >> 4, h = bh & 15;
    const int lane = threadIdx.x & 63;
    const int wave = threadIdx.x >> 6;
    const int r = lane >> 4;               // row within wave (0..3)
    const int c = lane & 15;               // col chunk (8 f32)
    const int i = rb8 * 16 + wave * 4 + r; // 0..127

    f32x4 S40, S41;
    {
        const float* s0 = &S0[((size_t)(bh * 128 + i)) * 128 + c * 8];
        S40 = *(const f32x4*)s0;
        S41 = *(const f32x4*)(s0 + 4);
    }

    const size_t hb = (size_t)(b * 2048) * 16 + h;
    const size_t STEP = 16 * 128;
    const float* kp = kn + hb * 128 + c * 8;
    const float* qp = qn + hb * 128 + c * 8;
    const float* vp = vv   + hb * 128 + i;
    const float* ap = adec + hb * 128 + i;
    const float* gp = gg   + hb * 128 + i;
    const float* bp = bet + hb;
    __hip_bfloat16* op = o + hb * 128 + i;

    f32x4 kA0, kA1, qA0, qA1; float vA, aA, gA, bA;
    f32x4 kB0, kB1, qB0, qB1; float vB, aB, gB, bB;
    f32x4 kC0, kC1, qC0, qC1; float vC, aC, gC, bC;
    f32x4 kD0, kD1, qD0, qD1; float vD, aD, gD, bD;

    kA0 = *(const f32x4*)(kp);            kA1 = *(const f32x4*)(kp + 4);
    qA0 = *(const f32x4*)(qp);            qA1 = *(const f32x4*)(qp + 4);
    vA = vp[0]; aA = ap[0]; gA = gp[0]; bA = bp[0];
    kB0 = *(const f32x4*)(kp + STEP);     kB1 = *(const f32x4*)(kp + STEP + 4);
    qB0 = *(const f32x4*)(qp + STEP);     qB1 = *(const f32x4*)(qp + STEP + 4);
    vB = vp[STEP]; aB = ap[STEP]; gB = gp[STEP]; bB = bp[16];
    kC0 = *(const f32x4*)(kp + 2 * STEP); kC1 = *(const f32x4*)(kp + 2 * STEP + 4);
    qC0 = *(const f32x4*)(qp + 2 * STEP); qC1 = *(const f32x4*)(qp + 2 * STEP + 4);
    vC = vp[2 * STEP]; aC = ap[2 * STEP]; gC = gp[2 * STEP]; bC = bp[32];

// compute step T from set C, prefetch step T+3 into set P (unclamped)
#define RBODY(T, C, P)                                                       \
    {                                                                        \
        const size_t nb_ = (size_t)((T) + 3) * STEP;                         \
        k##P##0 = *(const f32x4*)(kp + nb_);                                 \
        k##P##1 = *(const f32x4*)(kp + nb_ + 4);                             \
        q##P##0 = *(const f32x4*)(qp + nb_);                                 \
        q##P##1 = *(const f32x4*)(qp + nb_ + 4);                             \
        v##P = vp[nb_]; a##P = ap[nb_]; g##P = gp[nb_];                      \
        b##P = bp[(size_t)((T) + 3) * 16];                                   \
        f32x4 ps_ = S40 * k##C##0;                                           \
        ps_ = S41 * k##C##1 + ps_;                                           \
        float p_ = row_sum16((ps_[0] + ps_[1]) + (ps_[2] + ps_[3]));         \
        const float coef_ = b##C * (v##C - p_);                              \
        S40 = a##C * S40 + coef_ * k##C##0;                                  \
        S41 = a##C * S41 + coef_ * k##C##1;                                  \
        f32x4 os_ = S40 * q##C##0;                                           \
        os_ = S41 * q##C##1 + os_;                                           \
        float ov_ = row_sum16((os_[0] + os_[1]) + (os_[2] + os_[3]));        \
        if (c == 0) op[(size_t)(T) * STEP] = __float2bfloat16(ov_ * g##C);   \
    }

// compute only (no prefetch) — epilogue
#define RBODY_NP(T, C)                                                       \
    {                                                                        \
        f32x4 ps_ = S40 * k##C##0;                                           \
        ps_ = S41 * k##C##1 + ps_;                                           \
        float p_ = row_sum16((ps_[0] + ps_[1]) + (ps_[2] + ps_[3]));         \
        const float coef_ = b##C * (v##C - p_);                              \
        S40 = a##C * S40 + coef_ * k##C##0;                                  \
        S41 = a##C * S41 + coef_ * k##C##1;                                  \
        f32x4 os_ = S40 * q##C##0;                                           \
        os_ = S41 * q##C##1 + os_;                                           \
        float ov_ = row_sum16((os_[0] + os_[1]) + (os_[2] + os_[3]));        \
        if (c == 0) op[(size_t)(T) * STEP] = __float2bfloat16(ov_ * g##C);   \
    }

    for (int t = 0; t < 2044; t += 4) {
        RBODY(t,     A, D);
        RBODY(t + 1, B, A);
        RBODY(t + 2, C, B);
        RBODY(t + 3, D, C);
    }
    // after loop: A=2044, B=2045, C=2046; prefetch 2047 -> D in first epilogue step
    RBODY(2044, A, D);
    RBODY_NP(2045, B);
    RBODY_NP(2046, C);
    RBODY_NP(2047, D);
#undef RBODY
#undef RBODY_NP
}

// ----------------------------------------------------------------
extern "C" void kernel_launch(void* const* d_in, const int* in_sizes, int n_in,
                              void* d_out, int out_size, void* d_ws, size_t ws_size,
                              hipStream_t stream) {
    const float* x  = (const float*)d_in[0];
    const float* S0 = (const float*)d_in[1];
    const float* Wq = (const float*)d_in[2];
    const float* Wk = (const float*)d_in[3];
    const float* Wv = (const float*)d_in[4];
    const float* Wa = (const float*)d_in[5];
    const float* ba = (const float*)d_in[6];
    const float* Wb = (const float*)d_in[7];
    const float* bb = (const float*)d_in[8];
    const float* Wg = (const float*)d_in[9];
    const float* bg = (const float*)d_in[10];
    const float* Wo = (const float*)d_in[11];
    float* out = (float*)d_out;

    const int M = 4096, N = 2048, K = 2048;

    size_t off = 0;
    auto alloc = [&](size_t bytes) {
        void* p = (char*)d_ws + off;
        off += (bytes + 255) & ~(size_t)255;
        return p;
    };
    short* x_bf  = (short*)alloc((size_t)M * K * 2);  // later reused as o_bf
    short* Wq_bf = (short*)alloc((size_t)N * K * 2);
    short* Wk_bf = (short*)alloc((size_t)N * K * 2);
    short* Wv_bf = (short*)alloc((size_t)N * K * 2);
    short* Wa_bf = (short*)alloc((size_t)N * K * 2);
    short* Wg_bf = (short*)alloc((size_t)N * K * 2);
    short* Wo_bf = (short*)alloc((size_t)N * K * 2);
    float* qb    = (float*)alloc((size_t)M * N * 4);
    float* kb    = (float*)alloc((size_t)M * N * 4);
    float* vb    = (float*)alloc((size_t)M * N * 4);
    float* ab    = (float*)alloc((size_t)M * N * 4);
    float* gb    = (float*)alloc((size_t)M * N * 4);
    float* betab = (float*)alloc((size_t)M * 16 * 4);

    cast_bf16_kernel<<<dim3((M * K / 4 + 255) / 256), dim3(256), 0, stream>>>(x,  (__hip_bfloat16*)x_bf,  M * K);
    cast_bf16_kernel<<<dim3((N * K / 4 + 255) / 256), dim3(256), 0, stream>>>(Wq, (__hip_bfloat16*)Wq_bf, N * K);
    cast_bf16_kernel<<<dim3((N * K / 4 + 255) / 256), dim3(256), 0, stream>>>(Wk, (__hip_bfloat16*)Wk_bf, N * K);
    cast_bf16_kernel<<<dim3((N * K / 4 + 255) / 256), dim3(256), 0, stream>>>(Wv, (__hip_bfloat16*)Wv_bf, N * K);
    cast_bf16_kernel<<<dim3((N * K / 4 + 255) / 256), dim3(256), 0, stream>>>(Wa, (__hip_bfloat16*)Wa_bf, N * K);
    cast_bf16_kernel<<<dim3((N * K / 4 + 255) / 256), dim3(256), 0, stream>>>(Wg, (__hip_bfloat16*)Wg_bf, N * K);
    cast_bf16_kernel<<<dim3((N * K / 4 + 255) / 256), dim3(256), 0, stream>>>(Wo, (__hip_bfloat16*)Wo_bf, N * K);

    dim3 gdim(M / 128, N / 128), bdim(256);
    gemm_nt<0><<<gdim, bdim, 0, stream>>>(x_bf, Wq_bf, qb, nullptr, M, N, K);
    gemm_nt<0><<<gdim, bdim, 0, stream>>>(x_bf, Wk_bf, kb, nullptr, M, N, K);
    gemm_nt<0><<<gdim, bdim, 0, stream>>>(x_bf, Wv_bf, vb, nullptr, M, N, K);
    gemm_nt<1><<<gdim, bdim, 0, stream>>>(x_bf, Wa_bf, ab, ba, M, N, K);
    gemm_nt<1><<<gdim, bdim, 0, stream>>>(x_bf, Wg_bf, gb, bg, M, N, K);

    l2norm_kernel<<<dim3(M * 16 / 4), dim3(256), 0, stream>>>(qb);
    l2norm_kernel<<<dim3(M * 16 / 4), dim3(256), 0, stream>>>(kb);
    beta_kernel<<<dim3(M), dim3(256), 0, stream>>>(x, Wb, bb, betab);

    __hip_bfloat16* o_bf = (__hip_bfloat16*)x_bf;
    recurrence_kernel<<<dim3(256), dim3(256), 0, stream>>>(S0, qb, kb, vb, ab, betab, gb, o_bf);

    gemm_nt<0><<<gdim, bdim, 0, stream>>>((const short*)o_bf, Wo_bf, out, nullptr, M, N, K);
}